// Round 1
// baseline (256.703 us; speedup 1.0000x reference)
//
#include <hip/hip_runtime.h>
#include <hip/hip_bf16.h>

// MoE gate, fp32, B=65536 D=1024 E=8 K=2.
// Thread-per-row; per-wave private LDS double-buffer (NO barriers);
// global_load_lds(16B) with pre-swizzled global source so ds_read_b128 is
// bank-balanced; weights read via wave-uniform indices (scalar path).

#define BLOCK 256
#define CHUNK 32   // columns per K-chunk
#define C4S 8      // float4 per row per chunk

__global__ __launch_bounds__(BLOCK) void moe_gate_kernel(
    const float* __restrict__ x,
    const float* __restrict__ gate_w,
    const float* __restrict__ gate_b,
    const float* __restrict__ expert_w,
    const float* __restrict__ expert_b,
    const int* __restrict__ kp,
    float* __restrict__ out,
    int D)
{
    // 4 waves x 2 buffers x (64 rows x 8 float4) = 64 KiB
    __shared__ float4 smem[4][2][512];

    const int tid  = threadIdx.x;
    const int lane = tid & 63;
    const int wave = tid >> 6;
    const int rowBase = blockIdx.x * BLOCK;
    const int NC = D / CHUNK;

    const float* xw = x + (size_t)(rowBase + wave * 64) * (size_t)D;

    // staging geometry: wave-inst i writes slots [i*64, i*64+64), slot s = i*64+lane,
    // row_local = s>>3 = i*8 + (lane>>3), c4slot = lane&7.
    // LDS slot (row,c4slot) must contain global col4 = c*8 + (c4slot ^ (row&7)).
    const int rl_base = lane >> 3;            // row sub-index 0..7 (== row&7 for all i)
    const int srcc4   = (lane & 7) ^ rl_base; // swizzled source col4 within chunk

    float acc[16];
#pragma unroll
    for (int o = 0; o < 16; ++o) acc[o] = 0.f;

    auto stage = [&](int c, int b) {
#pragma unroll
        for (int i = 0; i < 8; ++i) {
            const int row_local = i * 8 + rl_base;
            const float* src = xw + (size_t)row_local * (size_t)D + (size_t)((c * C4S + srcc4) * 4);
            float4* dst = &smem[wave][b][i * 64 + lane];
            __builtin_amdgcn_global_load_lds(
                (const __attribute__((address_space(1))) void*)src,
                (__attribute__((address_space(3))) void*)dst, 16, 0, 0);
        }
    };

    const int sw = lane & 7;
    auto compute = [&](int b, int colBase) {
#pragma unroll
        for (int c4 = 0; c4 < 8; ++c4) {
            float4 xv = smem[wave][b][lane * 8 + (c4 ^ sw)];
            const int col = colBase + c4 * 4;        // wave-uniform
            const float* gw = gate_w + col;
            const float* ew = expert_w + col;
#pragma unroll
            for (int e = 0; e < 8; ++e) {
                const float* g  = gw + e * D;        // uniform address -> s_load
                acc[e] = fmaf(xv.x, g[0], acc[e]);
                acc[e] = fmaf(xv.y, g[1], acc[e]);
                acc[e] = fmaf(xv.z, g[2], acc[e]);
                acc[e] = fmaf(xv.w, g[3], acc[e]);
                const float* w2 = ew + e * D;
                acc[8 + e] = fmaf(xv.x, w2[0], acc[8 + e]);
                acc[8 + e] = fmaf(xv.y, w2[1], acc[8 + e]);
                acc[8 + e] = fmaf(xv.z, w2[2], acc[8 + e]);
                acc[8 + e] = fmaf(xv.w, w2[3], acc[8 + e]);
            }
        }
    };

    // pipeline: per-wave private buffers, counted vmcnt, no barriers
    stage(0, 0);
#pragma unroll 1
    for (int c = 0; c < NC - 1; ++c) {
        stage(c + 1, (c + 1) & 1);
        asm volatile("s_waitcnt vmcnt(8)" ::: "memory");  // chunk c landed; c+1 in flight
        compute(c & 1, c * CHUNK);
    }
    asm volatile("s_waitcnt vmcnt(0)" ::: "memory");
    compute((NC - 1) & 1, (NC - 1) * CHUNK);

    // ---- epilogue: bias, softmax over 8, top-k select (branchless, static idx) ----
    float gl[8], eo[8], p[8];
#pragma unroll
    for (int e = 0; e < 8; ++e) {
        gl[e] = acc[e] + gate_b[e];
        eo[e] = acc[8 + e] + expert_b[e];
    }
    float m = gl[0];
#pragma unroll
    for (int e = 1; e < 8; ++e) m = fmaxf(m, gl[e]);
    float Z = 0.f;
#pragma unroll
    for (int e = 0; e < 8; ++e) { p[e] = __expf(gl[e] - m); Z += p[e]; }

    const int k = *kp;
    float res = 0.f;
    if (k >= 8) {
#pragma unroll
        for (int e = 0; e < 8; ++e) res += p[e] * eo[e];
    } else {
        float pv[8];
#pragma unroll
        for (int e = 0; e < 8; ++e) pv[e] = p[e];
        for (int t = 0; t < k; ++t) {                 // k small (2)
            float bv = pv[0];
#pragma unroll
            for (int e = 1; e < 8; ++e) bv = fmaxf(bv, pv[e]);
            float sel = 0.f;
            bool found = false;
#pragma unroll
            for (int e = 0; e < 8; ++e) {             // first-match == lax.top_k tie rule
                bool is = (!found) && (pv[e] == bv);
                sel = is ? eo[e] : sel;
                pv[e] = is ? -1.f : pv[e];
                found = found || is;
            }
            res += bv * sel;
        }
    }
    out[rowBase + tid] = res / Z;
}

extern "C" void kernel_launch(void* const* d_in, const int* in_sizes, int n_in,
                              void* d_out, int out_size, void* d_ws, size_t ws_size,
                              hipStream_t stream) {
    const float* x  = (const float*)d_in[0];
    const float* gw = (const float*)d_in[1];
    const float* gb = (const float*)d_in[2];
    const float* ew = (const float*)d_in[3];
    const float* eb = (const float*)d_in[4];
    const int*   kp = (const int*)d_in[5];
    float* out = (float*)d_out;

    const int E = in_sizes[2];            // 8
    const int D = in_sizes[1] / E;        // 1024
    const int B = in_sizes[0] / D;        // 65536

    dim3 grid(B / BLOCK), block(BLOCK);
    moe_gate_kernel<<<grid, block, 0, stream>>>(x, gw, gb, ew, eb, kp, out, D);
}

// Round 2
// 55.920 us; speedup vs baseline: 4.5906x; 4.5906x over previous
//
#include <hip/hip_runtime.h>

// MoE gate fp32, B=65536 D=1024 E=8 K=2.
// 4 threads per row (16 row-groups x 4 col-splitters per wave) -> 4096 waves
// (16/CU), weights preloaded to LDS once, hot loop = coalesced x float4 load +
// 16 broadcast ds_read_b128 + 64 fma. Single cross-lane reduce at the end.

#define BLOCK 512
#define WAVES_PB (BLOCK / 64)           // 8
#define ROWS_PER_WAVE 16
#define ROWS_PER_BLOCK (WAVES_PB * ROWS_PER_WAVE)  // 128
#define DD 1024
#define EE 8

__global__ __launch_bounds__(BLOCK, 4) void moe_gate_kernel(
    const float* __restrict__ x,
    const float* __restrict__ gate_w,
    const float* __restrict__ gate_b,
    const float* __restrict__ expert_w,
    const float* __restrict__ expert_b,
    const int* __restrict__ kp,
    float* __restrict__ out)
{
    __shared__ float wlds[2 * EE * DD];   // 64 KiB: [gate(8x1024) | expert(8x1024)]

    const int tid = threadIdx.x;

    // ---- one-time weight preload (coalesced float4) ----
    {
        const float4* g4 = (const float4*)gate_w;
        const float4* e4 = (const float4*)expert_w;
        float4* w4 = (float4*)wlds;
#pragma unroll
        for (int i = 0; i < (EE * DD / 4) / BLOCK; ++i) {
            int idx = i * BLOCK + tid;
            w4[idx] = g4[idx];
            w4[EE * DD / 4 + idx] = e4[idx];
        }
    }
    __syncthreads();

    const int lane = tid & 63;
    const int wave = tid >> 6;
    const int g = lane >> 2;     // row within wave (0..15)
    const int j = lane & 3;      // column splitter (0..3)

    const int row = blockIdx.x * ROWS_PER_BLOCK + wave * ROWS_PER_WAVE + g;
    const float* xr = x + (size_t)row * DD + j * 4;

    const float* wg = wlds + j * 4;            // gate weights base for this lane
    const float* we = wlds + EE * DD + j * 4;  // expert weights base

    float acc[16];
#pragma unroll
    for (int i = 0; i < 16; ++i) acc[i] = 0.f;

    auto step = [&](int c, const float4& xv) {
        const int wc = c * 16;
#pragma unroll
        for (int e = 0; e < EE; ++e) {
            float4 w1 = *(const float4*)(wg + e * DD + wc);
            acc[e] = fmaf(xv.x, w1.x, acc[e]);
            acc[e] = fmaf(xv.y, w1.y, acc[e]);
            acc[e] = fmaf(xv.z, w1.z, acc[e]);
            acc[e] = fmaf(xv.w, w1.w, acc[e]);
            float4 w2 = *(const float4*)(we + e * DD + wc);
            acc[8 + e] = fmaf(xv.x, w2.x, acc[8 + e]);
            acc[8 + e] = fmaf(xv.y, w2.y, acc[8 + e]);
            acc[8 + e] = fmaf(xv.z, w2.z, acc[8 + e]);
            acc[8 + e] = fmaf(xv.w, w2.w, acc[8 + e]);
        }
    };

    // software-pipelined: prefetch next chunk's float4 while computing current
    float4 cur = *(const float4*)(xr);
#pragma unroll 1
    for (int c = 0; c < DD / 16 - 1; ++c) {
        float4 nxt = *(const float4*)(xr + (c + 1) * 16);
        step(c, cur);
        cur = nxt;
    }
    step(DD / 16 - 1, cur);

    // ---- reduce across the 4 column-splitter lanes (once per kernel) ----
#pragma unroll
    for (int i = 0; i < 16; ++i) {
        acc[i] += __shfl_xor(acc[i], 1);
        acc[i] += __shfl_xor(acc[i], 2);
    }

    if (j == 0) {
        float gl[8], eo[8], p[8];
#pragma unroll
        for (int e = 0; e < EE; ++e) {
            gl[e] = acc[e] + gate_b[e];
            eo[e] = acc[8 + e] + expert_b[e];
        }
        float m = gl[0];
#pragma unroll
        for (int e = 1; e < EE; ++e) m = fmaxf(m, gl[e]);
        float Z = 0.f;
#pragma unroll
        for (int e = 0; e < EE; ++e) { p[e] = __expf(gl[e] - m); Z += p[e]; }

        const int k = *kp;
        float res = 0.f;
        if (k >= EE) {
#pragma unroll
            for (int e = 0; e < EE; ++e) res += p[e] * eo[e];
        } else {
            float pv[8];
#pragma unroll
            for (int e = 0; e < EE; ++e) pv[e] = p[e];
            for (int t = 0; t < k; ++t) {
                float bv = pv[0];
#pragma unroll
                for (int e = 1; e < EE; ++e) bv = fmaxf(bv, pv[e]);
                float sel = 0.f;
                bool found = false;
#pragma unroll
                for (int e = 0; e < EE; ++e) {   // first-match == lax.top_k tie rule
                    bool is = (!found) && (pv[e] == bv);
                    sel = is ? eo[e] : sel;
                    pv[e] = is ? -1.f : pv[e];
                    found = found || is;
                }
                res += bv * sel;
            }
        }
        out[row] = res / Z;
    }
}

extern "C" void kernel_launch(void* const* d_in, const int* in_sizes, int n_in,
                              void* d_out, int out_size, void* d_ws, size_t ws_size,
                              hipStream_t stream) {
    const float* x  = (const float*)d_in[0];
    const float* gw = (const float*)d_in[1];
    const float* gb = (const float*)d_in[2];
    const float* ew = (const float*)d_in[3];
    const float* eb = (const float*)d_in[4];
    const int*   kp = (const int*)d_in[5];
    float* out = (float*)d_out;

    const int B = out_size;               // 65536
    dim3 grid(B / ROWS_PER_BLOCK), block(BLOCK);
    moe_gate_kernel<<<grid, block, 0, stream>>>(x, gw, gb, ew, eb, kp, out);
}

// Round 3
// 50.111 us; speedup vs baseline: 5.1227x; 1.1159x over previous
//
#include <hip/hip_runtime.h>

// MoE gate fp32, B=65536 D=1024 E=8 K=2.
// Wave = 8 row-slots x 8 col-splitters, 2 rows per lane (16 rows/wave).
// Weights preloaded to LDS once; each ds_read_b128 (128B contiguous,
// 8-way broadcast, conflict-free) feeds 8 fma -> LDS insts halved vs R2.
// x loads are 128B-contiguous per row. 4096 waves (16/CU).

#define BLOCK 512
#define DD 1024
#define EE 8
#define ROWS_PER_WAVE 16
#define ROWS_PER_BLOCK ((BLOCK / 64) * ROWS_PER_WAVE)   // 128

__global__ __launch_bounds__(BLOCK, 4) void moe_gate_kernel(
    const float* __restrict__ x,
    const float* __restrict__ gate_w,
    const float* __restrict__ gate_b,
    const float* __restrict__ expert_w,
    const float* __restrict__ expert_b,
    const int* __restrict__ kp,
    float* __restrict__ out)
{
    __shared__ float wlds[2 * EE * DD];   // 64 KiB: [gate 8x1024 | expert 8x1024]

    const int tid = threadIdx.x;

    // one-time weight preload (coalesced float4)
    {
        const float4* g4 = (const float4*)gate_w;
        const float4* e4 = (const float4*)expert_w;
        float4* w4 = (float4*)wlds;
#pragma unroll
        for (int i = 0; i < (EE * DD / 4) / BLOCK; ++i) {
            int idx = i * BLOCK + tid;
            w4[idx] = g4[idx];
            w4[EE * DD / 4 + idx] = e4[idx];
        }
    }
    __syncthreads();

    const int lane = tid & 63;
    const int wave = tid >> 6;
    const int s = lane >> 3;     // row-slot (0..7), owns rows {2s, 2s+1}
    const int j = lane & 7;      // column splitter (0..7), cols j*4 + c*32

    const int row0 = blockIdx.x * ROWS_PER_BLOCK + wave * ROWS_PER_WAVE + 2 * s;
    const float* xr0 = x + (size_t)row0 * DD + j * 4;
    const float* xr1 = xr0 + DD;

    const float* wb = wlds + j * 4;      // this lane's weight base

    float acc0[16], acc1[16];
#pragma unroll
    for (int i = 0; i < 16; ++i) { acc0[i] = 0.f; acc1[i] = 0.f; }

    auto step = [&](int c, const float4& x0, const float4& x1) {
        const int wc = c * 32;
#pragma unroll
        for (int o = 0; o < 16; ++o) {
            float4 w = *(const float4*)(wb + o * DD + wc);
            acc0[o] = fmaf(x0.x, w.x, acc0[o]);
            acc1[o] = fmaf(x1.x, w.x, acc1[o]);
            acc0[o] = fmaf(x0.y, w.y, acc0[o]);
            acc1[o] = fmaf(x1.y, w.y, acc1[o]);
            acc0[o] = fmaf(x0.z, w.z, acc0[o]);
            acc1[o] = fmaf(x1.z, w.z, acc1[o]);
            acc0[o] = fmaf(x0.w, w.w, acc0[o]);
            acc1[o] = fmaf(x1.w, w.w, acc1[o]);
        }
    };

    // software-pipelined: prefetch next chunk's x while computing current
    float4 a0 = *(const float4*)(xr0);
    float4 a1 = *(const float4*)(xr1);
#pragma unroll 1
    for (int c = 0; c < DD / 32 - 1; ++c) {
        float4 b0 = *(const float4*)(xr0 + (c + 1) * 32);
        float4 b1 = *(const float4*)(xr1 + (c + 1) * 32);
        step(c, a0, a1);
        a0 = b0; a1 = b1;
    }
    step(DD / 32 - 1, a0, a1);

    // reduce across the 8 column-splitter lanes (once per kernel)
#pragma unroll
    for (int i = 0; i < 16; ++i) {
        acc0[i] += __shfl_xor(acc0[i], 1);
        acc1[i] += __shfl_xor(acc1[i], 1);
        acc0[i] += __shfl_xor(acc0[i], 2);
        acc1[i] += __shfl_xor(acc1[i], 2);
        acc0[i] += __shfl_xor(acc0[i], 4);
        acc1[i] += __shfl_xor(acc1[i], 4);
    }

    if (j == 0) {
        const int k = *kp;
#pragma unroll
        for (int r = 0; r < 2; ++r) {
            const float* acc = r ? acc1 : acc0;
            float gl[8], eo[8], p[8];
#pragma unroll
            for (int e = 0; e < EE; ++e) {
                gl[e] = acc[e] + gate_b[e];
                eo[e] = acc[8 + e] + expert_b[e];
            }
            float m = gl[0];
#pragma unroll
            for (int e = 1; e < EE; ++e) m = fmaxf(m, gl[e]);
            float Z = 0.f;
#pragma unroll
            for (int e = 0; e < EE; ++e) { p[e] = __expf(gl[e] - m); Z += p[e]; }

            float res = 0.f;
            if (k >= EE) {
#pragma unroll
                for (int e = 0; e < EE; ++e) res += p[e] * eo[e];
            } else {
                float pv[8];
#pragma unroll
                for (int e = 0; e < EE; ++e) pv[e] = p[e];
                for (int t = 0; t < k; ++t) {
                    float bv = pv[0];
#pragma unroll
                    for (int e = 1; e < EE; ++e) bv = fmaxf(bv, pv[e]);
                    float sel = 0.f;
                    bool found = false;
#pragma unroll
                    for (int e = 0; e < EE; ++e) {   // first-match == lax.top_k tie rule
                        bool is = (!found) && (pv[e] == bv);
                        sel = is ? eo[e] : sel;
                        pv[e] = is ? -1.f : pv[e];
                        found = found || is;
                    }
                    res += bv * sel;
                }
            }
            out[row0 + r] = res / Z;
        }
    }
}

extern "C" void kernel_launch(void* const* d_in, const int* in_sizes, int n_in,
                              void* d_out, int out_size, void* d_ws, size_t ws_size,
                              hipStream_t stream) {
    const float* x  = (const float*)d_in[0];
    const float* gw = (const float*)d_in[1];
    const float* gb = (const float*)d_in[2];
    const float* ew = (const float*)d_in[3];
    const float* eb = (const float*)d_in[4];
    const int*   kp = (const int*)d_in[5];
    float* out = (float*)d_out;

    const int B = out_size;               // 65536
    dim3 grid(B / ROWS_PER_BLOCK), block(BLOCK);
    moe_gate_kernel<<<grid, block, 0, stream>>>(x, gw, gb, ew, eb, kp, out);
}